// Round 3
// baseline (2282.526 us; speedup 1.0000x reference)
//
#include <hip/hip_runtime.h>
#include <math.h>

#define EPS_BN 1e-5f

// Problem constants: B=32, NS=200, NQ=100, C=8, L=512, H=32, F=128, N_WAY=20
#define NSUP   6400
#define NQRY   3200
#define NSAMP  9600
#define NWAY   20
#define NSHOTB 200
#define NQB    100

// ===========================================================================
// Kernel 1: conv1 (8->32, L=512) + BN/ReLU/pool -> B1 (LDS)
//           conv2 (32->64, L=256) + BN/ReLU/pool -> Y2 (global)
// One block/sample, 256 threads. LDS ~50KB -> 3 blocks/CU.
// __launch_bounds__(256,3): 3 waves/EU min -> VGPR cap ~170, so the 64 fp32
// accumulators live in arch VGPRs (round-2 showed VGPR_Count=60 -> AGPR
// shuffling around every FMA).
// ===========================================================================
__global__ __launch_bounds__(256, 3) void conv12_kernel(
    const float* __restrict__ s_img, const float* __restrict__ q_img,
    const float* __restrict__ pw1, const float* __restrict__ pb1,
    const float* __restrict__ pg1, const float* __restrict__ pbe1,
    const float* __restrict__ pm1, const float* __restrict__ pv1,
    const float* __restrict__ pw2, const float* __restrict__ pb2,
    const float* __restrict__ pg2, const float* __restrict__ pbe2,
    const float* __restrict__ pm2, const float* __restrict__ pv2,
    float* __restrict__ Y2)
{
    __shared__ float I[8 * 514];      // halo cols
    __shared__ float B1[32 * 258];    // halo cols
    __shared__ float sc1[32], sh1[32], sc2[64], sh2[64];

    const int tid = threadIdx.x;
    const int sid = blockIdx.x;
    const float* xin = (sid < NSUP) ? (s_img + (size_t)sid * 4096)
                                    : (q_img + (size_t)(sid - NSUP) * 4096);

    if (tid < 32) {
        float s = pg1[tid] * rsqrtf(pv1[tid] + EPS_BN);
        sc1[tid] = s; sh1[tid] = (pb1[tid] - pm1[tid]) * s + pbe1[tid];
    } else if (tid < 96) {
        int c = tid - 32;
        float s = pg2[c] * rsqrtf(pv2[c] + EPS_BN);
        sc2[c] = s; sh2[c] = (pb2[c] - pm2[c]) * s + pbe2[c];
    }
    if (tid < 32) { B1[tid*258] = 0.f; B1[tid*258 + 257] = 0.f; }
    if (tid < 8)  { I[tid*514] = 0.f;  I[tid*514 + 513] = 0.f; }
    // staging: scalar coalesced loads, stride-1 LDS writes (conflict-free)
    #pragma unroll
    for (int k = 0; k < 16; ++k) {
        int p = k*256 + tid;                 // 4096 floats
        float v = xin[p];
        int ci = p >> 9;
        int l  = p & 511;
        I[ci*514 + 1 + l] = v;
    }
    __syncthreads();

    // ---- conv1 ----
    {
        const int lp = tid;
        float a0[32], a1[32];
        #pragma unroll
        for (int c = 0; c < 32; ++c) { a0[c] = 0.f; a1[c] = 0.f; }
        #pragma unroll
        for (int ci = 0; ci < 8; ++ci) {
            const float x0 = I[ci*514 + 2*lp + 0];
            const float x1 = I[ci*514 + 2*lp + 1];
            const float x2 = I[ci*514 + 2*lp + 2];
            const float x3 = I[ci*514 + 2*lp + 3];
            #pragma unroll
            for (int co = 0; co < 32; ++co) {
                const float W0 = pw1[(co*8 + ci)*3 + 0];
                const float W1 = pw1[(co*8 + ci)*3 + 1];
                const float W2 = pw1[(co*8 + ci)*3 + 2];
                a0[co] += W0*x0 + W1*x1 + W2*x2;
                a1[co] += W0*x1 + W1*x2 + W2*x3;
            }
        }
        #pragma unroll
        for (int co = 0; co < 32; ++co) {
            float v = fmaxf(a0[co]*sc1[co] + sh1[co], a1[co]*sc1[co] + sh1[co]);
            B1[co*258 + 1 + lp] = fmaxf(v, 0.f);
        }
    }
    __syncthreads();

    // ---- conv2 ----
    {
        const int lp = tid & 127;
        const int cobase = __builtin_amdgcn_readfirstlane(tid >> 7) * 32;
        float a0[32], a1[32];
        #pragma unroll
        for (int c = 0; c < 32; ++c) { a0[c] = 0.f; a1[c] = 0.f; }
        for (int ci = 0; ci < 32; ++ci) {
            const float x0 = B1[ci*258 + 2*lp + 0];
            const float x1 = B1[ci*258 + 2*lp + 1];
            const float x2 = B1[ci*258 + 2*lp + 2];
            const float x3 = B1[ci*258 + 2*lp + 3];
            #pragma unroll
            for (int j = 0; j < 32; ++j) {
                const int co = cobase + j;
                const float W0 = pw2[(co*32 + ci)*3 + 0];
                const float W1 = pw2[(co*32 + ci)*3 + 1];
                const float W2 = pw2[(co*32 + ci)*3 + 2];
                a0[j] += W0*x0 + W1*x1 + W2*x2;
                a1[j] += W0*x1 + W1*x2 + W2*x3;
            }
        }
        float* ybase = Y2 + (size_t)sid * 8192;
        #pragma unroll
        for (int j = 0; j < 32; ++j) {
            const int co = cobase + j;
            float v = fmaxf(a0[j]*sc2[co] + sh2[co], a1[j]*sc2[co] + sh2[co]);
            ybase[co*128 + lp] = fmaxf(v, 0.f);
        }
    }
}

// ===========================================================================
// Kernel 2: conv3 (64->128, L=128) + BN/ReLU/pool + mean + linear + BN + ReLU
// + L2 normalize. LDS ~35KB -> 4 blocks/CU. __launch_bounds__(256,4): VGPR
// cap 128 = exactly the LDS-allowed occupancy, accumulators stay in VGPRs.
// ===========================================================================
__global__ __launch_bounds__(256, 4) void conv3tail_kernel(
    const float* __restrict__ Y2,
    const float* __restrict__ pw3, const float* __restrict__ pb3,
    const float* __restrict__ pg3, const float* __restrict__ pbe3,
    const float* __restrict__ pm3, const float* __restrict__ pv3,
    const float* __restrict__ pwf, const float* __restrict__ pbf,
    const float* __restrict__ pgf, const float* __restrict__ pbef,
    const float* __restrict__ pmf, const float* __restrict__ pvf,
    float* __restrict__ feat_out)
{
    __shared__ float S[64 * 130];     // staged Y2 w/ halos; later B3 (128x64)
    __shared__ float sc3[128], sh3[128];
    __shared__ float featm[128], featr[128];

    const int tid = threadIdx.x;
    const int sid = blockIdx.x;

    if (tid < 128) {
        float s = pg3[tid] * rsqrtf(pv3[tid] + EPS_BN);
        sc3[tid] = s; sh3[tid] = (pb3[tid] - pm3[tid]) * s + pbe3[tid];
    }
    if (tid < 64) { S[tid*130] = 0.f; S[tid*130 + 129] = 0.f; }
    const float* ybase = Y2 + (size_t)sid * 8192;
    // staging: scalar coalesced loads, stride-1 LDS writes (conflict-free)
    #pragma unroll
    for (int k = 0; k < 32; ++k) {
        int p = k*256 + tid;                 // 8192 floats
        float v = ybase[p];
        int ci = p >> 7;
        int l  = p & 127;
        S[ci*130 + 1 + l] = v;
    }
    __syncthreads();

    // ---- conv3 ----
    float pooled[32];
    const int lp = tid & 63;
    const int cobase = __builtin_amdgcn_readfirstlane(tid >> 6) * 32;
    {
        float a0[32], a1[32];
        #pragma unroll
        for (int c = 0; c < 32; ++c) { a0[c] = 0.f; a1[c] = 0.f; }
        for (int ci = 0; ci < 64; ++ci) {
            const float x0 = S[ci*130 + 2*lp + 0];
            const float x1 = S[ci*130 + 2*lp + 1];
            const float x2 = S[ci*130 + 2*lp + 2];
            const float x3 = S[ci*130 + 2*lp + 3];
            #pragma unroll
            for (int j = 0; j < 32; ++j) {
                const int co = cobase + j;
                const float W0 = pw3[(co*64 + ci)*3 + 0];
                const float W1 = pw3[(co*64 + ci)*3 + 1];
                const float W2 = pw3[(co*64 + ci)*3 + 2];
                a0[j] += W0*x0 + W1*x1 + W2*x2;
                a1[j] += W0*x1 + W1*x2 + W2*x3;
            }
        }
        #pragma unroll
        for (int j = 0; j < 32; ++j) {
            const int co = cobase + j;
            float v = fmaxf(a0[j]*sc3[co] + sh3[co], a1[j]*sc3[co] + sh3[co]);
            pooled[j] = fmaxf(v, 0.f);
        }
    }
    __syncthreads();   // staged Y2 reads done; safe to overwrite with B3
    #pragma unroll
    for (int j = 0; j < 32; ++j) S[(cobase + j)*64 + lp] = pooled[j];
    __syncthreads();

    // ---- mean over L=64 ----
    if (tid < 128) {
        float s = 0.f;
        for (int i = 0; i < 64; ++i) {
            int l = (i + tid) & 63;
            s += S[tid*64 + l];
        }
        featm[tid] = s * (1.0f / 64.0f);
    }
    __syncthreads();

    // ---- linear 128->128 + BN + ReLU ----
    if (tid < 128) {
        const float* wr = pwf + (size_t)tid * 128;
        float s = 0.f;
        #pragma unroll 4
        for (int i = 0; i < 128; i += 4) {
            float4 w4 = *(const float4*)(wr + i);
            s += w4.x*featm[i] + w4.y*featm[i+1] + w4.z*featm[i+2] + w4.w*featm[i+3];
        }
        s += pbf[tid];
        s = (s - pmf[tid]) * (pgf[tid] * rsqrtf(pvf[tid] + EPS_BN)) + pbef[tid];
        featr[tid] = fmaxf(s, 0.f);
    }
    __syncthreads();

    // ---- L2 normalize ----
    if (tid < 128) {
        float ss = 0.f;
        for (int i = 0; i < 128; ++i) ss += featr[i] * featr[i];
        float n = fmaxf(sqrtf(ss), 1e-12f);
        feat_out[(size_t)sid * 128 + tid] = featr[tid] / n;
    }
}

// ===========================================================================
// MONOLITHIC FALLBACK — only if ws_size can't hold the Y2 intermediate.
// ===========================================================================
__global__ __launch_bounds__(256, 2) void encoder_mono(
    const float* __restrict__ s_img, const float* __restrict__ q_img,
    const float* __restrict__ pw1, const float* __restrict__ pb1,
    const float* __restrict__ pg1, const float* __restrict__ pbe1,
    const float* __restrict__ pm1, const float* __restrict__ pv1,
    const float* __restrict__ pw2, const float* __restrict__ pb2,
    const float* __restrict__ pg2, const float* __restrict__ pbe2,
    const float* __restrict__ pm2, const float* __restrict__ pv2,
    const float* __restrict__ pw3, const float* __restrict__ pb3,
    const float* __restrict__ pg3, const float* __restrict__ pbe3,
    const float* __restrict__ pm3, const float* __restrict__ pv3,
    const float* __restrict__ pwf, const float* __restrict__ pbf,
    const float* __restrict__ pgf, const float* __restrict__ pbef,
    const float* __restrict__ pmf, const float* __restrict__ pvf,
    float* __restrict__ feat_out)
{
    __shared__ float smem[16576];
    __shared__ float sc1[32], sh1[32], sc2[64], sh2[64], sc3[128], sh3[128];
    __shared__ float featm[128], featr[128];

    float* const I  = smem;
    float* const B2 = smem;
    float* const B1 = smem + 8320;
    float* const B3 = smem + 8320;

    const int tid = threadIdx.x;
    const int sid = blockIdx.x;
    const float* xin = (sid < NSUP) ? (s_img + (size_t)sid * 4096)
                                    : (q_img + (size_t)(sid - NSUP) * 4096);

    if (tid < 32) {
        float s = pg1[tid] * rsqrtf(pv1[tid] + EPS_BN);
        sc1[tid] = s; sh1[tid] = (pb1[tid] - pm1[tid]) * s + pbe1[tid];
    } else if (tid < 96) {
        int c = tid - 32;
        float s = pg2[c] * rsqrtf(pv2[c] + EPS_BN);
        sc2[c] = s; sh2[c] = (pb2[c] - pm2[c]) * s + pbe2[c];
    } else if (tid < 224) {
        int c = tid - 96;
        float s = pg3[c] * rsqrtf(pv3[c] + EPS_BN);
        sc3[c] = s; sh3[c] = (pb3[c] - pm3[c]) * s + pbe3[c];
    }
    if (tid < 32) { B1[tid*258] = 0.f; B1[tid*258 + 257] = 0.f; }
    #pragma unroll
    for (int k = 0; k < 16; ++k) {
        int p = k*256 + tid;
        float v = xin[p];
        int ci = p >> 9;
        int l  = p & 511;
        I[ci*514 + 1 + l] = v;
    }
    if (tid < 8) { I[tid*514] = 0.f; I[tid*514 + 513] = 0.f; }
    __syncthreads();

    {
        const int lp = tid;
        float a0[32], a1[32];
        #pragma unroll
        for (int c = 0; c < 32; ++c) { a0[c] = 0.f; a1[c] = 0.f; }
        #pragma unroll
        for (int ci = 0; ci < 8; ++ci) {
            const float x0 = I[ci*514 + 2*lp + 0];
            const float x1 = I[ci*514 + 2*lp + 1];
            const float x2 = I[ci*514 + 2*lp + 2];
            const float x3 = I[ci*514 + 2*lp + 3];
            #pragma unroll
            for (int co = 0; co < 32; ++co) {
                const float W0 = pw1[(co*8 + ci)*3 + 0];
                const float W1 = pw1[(co*8 + ci)*3 + 1];
                const float W2 = pw1[(co*8 + ci)*3 + 2];
                a0[co] += W0*x0 + W1*x1 + W2*x2;
                a1[co] += W0*x1 + W1*x2 + W2*x3;
            }
        }
        #pragma unroll
        for (int co = 0; co < 32; ++co) {
            float v = fmaxf(a0[co]*sc1[co] + sh1[co], a1[co]*sc1[co] + sh1[co]);
            B1[co*258 + 1 + lp] = fmaxf(v, 0.f);
        }
    }
    __syncthreads();

    {
        if (tid < 64) { B2[tid*130] = 0.f; B2[tid*130 + 129] = 0.f; }
        const int lp = tid & 127;
        const int cobase = __builtin_amdgcn_readfirstlane(tid >> 7) * 32;
        float a0[32], a1[32];
        #pragma unroll
        for (int c = 0; c < 32; ++c) { a0[c] = 0.f; a1[c] = 0.f; }
        for (int ci = 0; ci < 32; ++ci) {
            const float x0 = B1[ci*258 + 2*lp + 0];
            const float x1 = B1[ci*258 + 2*lp + 1];
            const float x2 = B1[ci*258 + 2*lp + 2];
            const float x3 = B1[ci*258 + 2*lp + 3];
            #pragma unroll
            for (int j = 0; j < 32; ++j) {
                const int co = cobase + j;
                const float W0 = pw2[(co*32 + ci)*3 + 0];
                const float W1 = pw2[(co*32 + ci)*3 + 1];
                const float W2 = pw2[(co*32 + ci)*3 + 2];
                a0[j] += W0*x0 + W1*x1 + W2*x2;
                a1[j] += W0*x1 + W1*x2 + W2*x3;
            }
        }
        #pragma unroll
        for (int j = 0; j < 32; ++j) {
            const int co = cobase + j;
            float v = fmaxf(a0[j]*sc2[co] + sh2[co], a1[j]*sc2[co] + sh2[co]);
            B2[co*130 + 1 + lp] = fmaxf(v, 0.f);
        }
    }
    __syncthreads();

    {
        const int lp = tid & 63;
        const int cobase = __builtin_amdgcn_readfirstlane(tid >> 6) * 32;
        float a0[32], a1[32];
        #pragma unroll
        for (int c = 0; c < 32; ++c) { a0[c] = 0.f; a1[c] = 0.f; }
        for (int ci = 0; ci < 64; ++ci) {
            const float x0 = B2[ci*130 + 2*lp + 0];
            const float x1 = B2[ci*130 + 2*lp + 1];
            const float x2 = B2[ci*130 + 2*lp + 2];
            const float x3 = B2[ci*130 + 2*lp + 3];
            #pragma unroll
            for (int j = 0; j < 32; ++j) {
                const int co = cobase + j;
                const float W0 = pw3[(co*64 + ci)*3 + 0];
                const float W1 = pw3[(co*64 + ci)*3 + 1];
                const float W2 = pw3[(co*64 + ci)*3 + 2];
                a0[j] += W0*x0 + W1*x1 + W2*x2;
                a1[j] += W0*x1 + W1*x2 + W2*x3;
            }
        }
        #pragma unroll
        for (int j = 0; j < 32; ++j) {
            const int co = cobase + j;
            float v = fmaxf(a0[j]*sc3[co] + sh3[co], a1[j]*sc3[co] + sh3[co]);
            B3[co*64 + lp] = fmaxf(v, 0.f);
        }
    }
    __syncthreads();

    if (tid < 128) {
        float s = 0.f;
        for (int i = 0; i < 64; ++i) {
            int lp = (i + tid) & 63;
            s += B3[tid*64 + lp];
        }
        featm[tid] = s * (1.0f / 64.0f);
    }
    __syncthreads();

    if (tid < 128) {
        const float* wr = pwf + (size_t)tid * 128;
        float s = 0.f;
        #pragma unroll 4
        for (int i = 0; i < 128; i += 4) {
            float4 w4 = *(const float4*)(wr + i);
            s += w4.x*featm[i] + w4.y*featm[i+1] + w4.z*featm[i+2] + w4.w*featm[i+3];
        }
        s += pbf[tid];
        s = (s - pmf[tid]) * (pgf[tid] * rsqrtf(pvf[tid] + EPS_BN)) + pbef[tid];
        featr[tid] = fmaxf(s, 0.f);
    }
    __syncthreads();

    if (tid < 128) {
        float ss = 0.f;
        for (int i = 0; i < 128; ++i) ss += featr[i] * featr[i];
        float n = fmaxf(sqrtf(ss), 1e-12f);
        feat_out[(size_t)sid * 128 + tid] = featr[tid] / n;
    }
}

// ---------------------------------------------------------------------------
__global__ __launch_bounds__(128) void proto_kernel(
    const float* __restrict__ feat_s, const int* __restrict__ s_lab,
    float* __restrict__ protos)
{
    const int b = blockIdx.x / NWAY;
    const int w = blockIdx.x % NWAY;
    const int f = threadIdx.x;
    const float* sf = feat_s + (size_t)b * NSHOTB * 128;
    const int* lab = s_lab + b * NSHOTB;
    float acc = 0.f;
    int cnt = 0;
    for (int s = 0; s < NSHOTB; ++s) {
        int lv = lab[s];
        if (lv == w) { acc += sf[s*128 + f]; cnt++; }
    }
    protos[(size_t)blockIdx.x * 128 + f] = acc / (float)cnt;
}

__global__ __launch_bounds__(256) void dist_kernel(
    const float* __restrict__ feat_q, const float* __restrict__ protos,
    float* __restrict__ out)
{
    int idx = blockIdx.x * 256 + threadIdx.x;
    if (idx >= 32 * NQB * NWAY) return;
    int b = idx / (NQB * NWAY);
    int r = idx - b * (NQB * NWAY);
    int q = r / NWAY;
    int w = r - q * NWAY;
    const float* qf = feat_q + (size_t)(b * NQB + q) * 128;
    const float* pp = protos + (size_t)(b * NWAY + w) * 128;
    float d2 = 0.f;
    #pragma unroll 4
    for (int i = 0; i < 128; ++i) { float d = qf[i] - pp[i]; d2 += d * d; }
    out[idx] = -sqrtf(fmaxf(d2, 0.f));
}

// ---------------------------------------------------------------------------
extern "C" void kernel_launch(void* const* d_in, const int* in_sizes, int n_in,
                              void* d_out, int out_size, void* d_ws, size_t ws_size,
                              hipStream_t stream) {
    const float* s_img = (const float*)d_in[0];
    const float* q_img = (const float*)d_in[1];
    const int*   s_lab = (const int*)d_in[2];
    const float* pw1  = (const float*)d_in[3];
    const float* pb1  = (const float*)d_in[4];
    const float* pg1  = (const float*)d_in[5];
    const float* pbe1 = (const float*)d_in[6];
    const float* pm1  = (const float*)d_in[7];
    const float* pv1  = (const float*)d_in[8];
    const float* pw2  = (const float*)d_in[9];
    const float* pb2  = (const float*)d_in[10];
    const float* pg2  = (const float*)d_in[11];
    const float* pbe2 = (const float*)d_in[12];
    const float* pm2  = (const float*)d_in[13];
    const float* pv2  = (const float*)d_in[14];
    const float* pw3  = (const float*)d_in[15];
    const float* pb3  = (const float*)d_in[16];
    const float* pg3  = (const float*)d_in[17];
    const float* pbe3 = (const float*)d_in[18];
    const float* pm3  = (const float*)d_in[19];
    const float* pv3  = (const float*)d_in[20];
    const float* pwf  = (const float*)d_in[21];
    const float* pbf  = (const float*)d_in[22];
    const float* pgf  = (const float*)d_in[23];
    const float* pbef = (const float*)d_in[24];
    const float* pmf  = (const float*)d_in[25];
    const float* pvf  = (const float*)d_in[26];

    const size_t y2_elems   = (size_t)NSAMP * 8192;
    const size_t feat_elems = (size_t)NSAMP * 128;
    const size_t prot_elems = (size_t)32 * NWAY * 128;
    const size_t need_split = (y2_elems + feat_elems + prot_elems) * sizeof(float);

    float* out = (float*)d_out;

    if (ws_size >= need_split) {
        float* Y2     = (float*)d_ws;
        float* feat   = Y2 + y2_elems;
        float* protos = feat + feat_elems;

        conv12_kernel<<<NSAMP, 256, 0, stream>>>(
            s_img, q_img,
            pw1, pb1, pg1, pbe1, pm1, pv1,
            pw2, pb2, pg2, pbe2, pm2, pv2,
            Y2);
        conv3tail_kernel<<<NSAMP, 256, 0, stream>>>(
            Y2,
            pw3, pb3, pg3, pbe3, pm3, pv3,
            pwf, pbf, pgf, pbef, pmf, pvf,
            feat);
        proto_kernel<<<32 * NWAY, 128, 0, stream>>>(feat, s_lab, protos);
        dist_kernel<<<(32 * NQB * NWAY + 255) / 256, 256, 0, stream>>>(
            feat + (size_t)NSUP * 128, protos, out);
    } else {
        float* feat   = (float*)d_ws;
        float* protos = feat + feat_elems;

        encoder_mono<<<NSAMP, 256, 0, stream>>>(
            s_img, q_img,
            pw1, pb1, pg1, pbe1, pm1, pv1,
            pw2, pb2, pg2, pbe2, pm2, pv2,
            pw3, pb3, pg3, pbe3, pm3, pv3,
            pwf, pbf, pgf, pbef, pmf, pvf,
            feat);
        proto_kernel<<<32 * NWAY, 128, 0, stream>>>(feat, s_lab, protos);
        dist_kernel<<<(32 * NQB * NWAY + 255) / 256, 256, 0, stream>>>(
            feat + (size_t)NSUP * 128, protos, out);
    }
}

// Round 4
// 1225.744 us; speedup vs baseline: 1.8622x; 1.8622x over previous
//
#include <hip/hip_runtime.h>
#include <math.h>

#define EPS_BN 1e-5f

// Problem constants: B=32, NS=200, NQ=100, C=8, L=512, H=32, F=128, N_WAY=20
#define NSUP   6400
#define NQRY   3200
#define NSAMP  9600
#define NWAY   20
#define NSHOTB 200
#define NQB    100

using short8  = __attribute__((ext_vector_type(8))) short;
using floatx4 = __attribute__((ext_vector_type(4))) float;

// split x into hi/lo bf16 (RNE both): x ~= h + l, |err| ~ 2^-17 |x|
__device__ __forceinline__ void bf16_split(float x, unsigned& uh, unsigned& ul) {
    unsigned u = __float_as_uint(x);
    uh = (u + 0x7FFFu + ((u >> 16) & 1u)) >> 16;
    float hf = __uint_as_float(uh << 16);
    float e  = x - hf;
    unsigned ue = __float_as_uint(e);
    ul = (ue + 0x7FFFu + ((ue >> 16) & 1u)) >> 16;
}

// ===========================================================================
// prep: reformat conv3 weights (fp32 [128][64][3]) into MFMA B-fragment order,
// split hi/lo bf16. Frag id f = ((t*2+ks)*8 + nt)*2 + hl; element (lane,j) at
// Wf3[f*512 + lane*8 + j] = W[co = nt*16 + (lane&15)][ci = ks*32+(lane>>4)*8+j][t]
// ===========================================================================
__global__ __launch_bounds__(256) void prep_w3_kernel(
    const float* __restrict__ w3, unsigned short* __restrict__ Wf3)
{
    int e = blockIdx.x * 512 + threadIdx.x;   // grid 96, 2 elems/thread
    #pragma unroll
    for (int r = 0; r < 2; ++r, e += 256) {
        int frag = e >> 9;
        int off  = e & 511;
        int lane = off >> 3, j = off & 7;
        int hl = frag & 1;
        int f2 = frag >> 1;
        int nt = f2 & 7;
        int f3 = f2 >> 3;
        int ks = f3 & 1;
        int t  = f3 >> 1;
        int co = nt * 16 + (lane & 15);
        int ci = ks * 32 + (lane >> 4) * 8 + j;
        float x = w3[(co * 64 + ci) * 3 + t];
        unsigned uh, ul;
        bf16_split(x, uh, ul);
        Wf3[e] = (unsigned short)(hl ? ul : uh);
    }
}

// ===========================================================================
// Kernel 1 (round-2 version, measured ~820us): conv1 + conv2 vector fp32.
// ===========================================================================
__global__ __launch_bounds__(256) void conv12_kernel(
    const float* __restrict__ s_img, const float* __restrict__ q_img,
    const float* __restrict__ pw1, const float* __restrict__ pb1,
    const float* __restrict__ pg1, const float* __restrict__ pbe1,
    const float* __restrict__ pm1, const float* __restrict__ pv1,
    const float* __restrict__ pw2, const float* __restrict__ pb2,
    const float* __restrict__ pg2, const float* __restrict__ pbe2,
    const float* __restrict__ pm2, const float* __restrict__ pv2,
    float* __restrict__ Y2)
{
    __shared__ float I[8 * 514];
    __shared__ float B1[32 * 258];
    __shared__ float sc1[32], sh1[32], sc2[64], sh2[64];

    const int tid = threadIdx.x;
    const int sid = blockIdx.x;
    const float* xin = (sid < NSUP) ? (s_img + (size_t)sid * 4096)
                                    : (q_img + (size_t)(sid - NSUP) * 4096);

    if (tid < 32) {
        float s = pg1[tid] * rsqrtf(pv1[tid] + EPS_BN);
        sc1[tid] = s; sh1[tid] = (pb1[tid] - pm1[tid]) * s + pbe1[tid];
    } else if (tid < 96) {
        int c = tid - 32;
        float s = pg2[c] * rsqrtf(pv2[c] + EPS_BN);
        sc2[c] = s; sh2[c] = (pb2[c] - pm2[c]) * s + pbe2[c];
    }
    if (tid < 32) { B1[tid*258] = 0.f; B1[tid*258 + 257] = 0.f; }
    if (tid < 8)  { I[tid*514] = 0.f;  I[tid*514 + 513] = 0.f; }
    #pragma unroll
    for (int k = 0; k < 4; ++k) {
        int p = k*256 + tid;
        float4 v = ((const float4*)xin)[p];
        int fi = p * 4;
        int ci = fi >> 9;
        int l  = fi & 511;
        float* dst = &I[ci*514 + 1 + l];
        dst[0] = v.x; dst[1] = v.y; dst[2] = v.z; dst[3] = v.w;
    }
    __syncthreads();

    // ---- conv1 ----
    {
        const int lp = tid;
        float a0[32], a1[32];
        #pragma unroll
        for (int c = 0; c < 32; ++c) { a0[c] = 0.f; a1[c] = 0.f; }
        #pragma unroll
        for (int ci = 0; ci < 8; ++ci) {
            const float x0 = I[ci*514 + 2*lp + 0];
            const float x1 = I[ci*514 + 2*lp + 1];
            const float x2 = I[ci*514 + 2*lp + 2];
            const float x3 = I[ci*514 + 2*lp + 3];
            #pragma unroll
            for (int co = 0; co < 32; ++co) {
                const float W0 = pw1[(co*8 + ci)*3 + 0];
                const float W1 = pw1[(co*8 + ci)*3 + 1];
                const float W2 = pw1[(co*8 + ci)*3 + 2];
                a0[co] += W0*x0 + W1*x1 + W2*x2;
                a1[co] += W0*x1 + W1*x2 + W2*x3;
            }
        }
        #pragma unroll
        for (int co = 0; co < 32; ++co) {
            float v = fmaxf(a0[co]*sc1[co] + sh1[co], a1[co]*sc1[co] + sh1[co]);
            B1[co*258 + 1 + lp] = fmaxf(v, 0.f);
        }
    }
    __syncthreads();

    // ---- conv2 ----
    {
        const int lp = tid & 127;
        const int cobase = __builtin_amdgcn_readfirstlane(tid >> 7) * 32;
        float a0[32], a1[32];
        #pragma unroll
        for (int c = 0; c < 32; ++c) { a0[c] = 0.f; a1[c] = 0.f; }
        for (int ci = 0; ci < 32; ++ci) {
            const float x0 = B1[ci*258 + 2*lp + 0];
            const float x1 = B1[ci*258 + 2*lp + 1];
            const float x2 = B1[ci*258 + 2*lp + 2];
            const float x3 = B1[ci*258 + 2*lp + 3];
            #pragma unroll
            for (int j = 0; j < 32; ++j) {
                const int co = cobase + j;
                const float W0 = pw2[(co*32 + ci)*3 + 0];
                const float W1 = pw2[(co*32 + ci)*3 + 1];
                const float W2 = pw2[(co*32 + ci)*3 + 2];
                a0[j] += W0*x0 + W1*x1 + W2*x2;
                a1[j] += W0*x1 + W1*x2 + W2*x3;
            }
        }
        float* ybase = Y2 + (size_t)sid * 8192;
        #pragma unroll
        for (int j = 0; j < 32; ++j) {
            const int co = cobase + j;
            float v = fmaxf(a0[j]*sc2[co] + sh2[co], a1[j]*sc2[co] + sh2[co]);
            ybase[co*128 + lp] = fmaxf(v, 0.f);
        }
    }
}

// ===========================================================================
// Kernel 2 (MFMA): conv3 via split-bf16 16x16x32 MFMA + BN/ReLU/pool + mean
// fused into the C-fragment epilogue, then linear/BN/ReLU/normalize.
// GEMM: D[l][co] = sum_{ci,t} Xt[l+t][ci] * W[co][ci][t]; A = Xt (m = l),
// B = W-frags (n = co, preformatted). Wave owns n-tiles {2w, 2w+1} x all 8
// m-tiles. acc: 16 tiles x 4 f32. LDS ~48 KB -> 3 blocks/CU.
// ===========================================================================
__global__ __launch_bounds__(256, 3) void conv3tail_kernel(
    const float* __restrict__ Y2, const unsigned short* __restrict__ Wf3,
    const float* __restrict__ pg3, const float* __restrict__ pbe3,
    const float* __restrict__ pb3, const float* __restrict__ pm3,
    const float* __restrict__ pv3,
    const float* __restrict__ pwf, const float* __restrict__ pbf,
    const float* __restrict__ pgf, const float* __restrict__ pbef,
    const float* __restrict__ pmf, const float* __restrict__ pvf,
    float* __restrict__ feat_out)
{
    // Xt rows: l' = l_in + 1 (halo rows 0 and 129 zero), cols: ci (64) + pad 8
    // row stride 72 bf16 = 144 B (16B-aligned, gcd(36,32)=4 -> uniform banks)
    __shared__ __align__(16) short Xh[130 * 72];
    __shared__ __align__(16) short Xl[130 * 72];
    __shared__ __align__(16) float S[16 * 132];   // fp32 transpose staging chunk
    __shared__ float sc3[128], sh3[128], featm[128], featr[128];

    const int tid  = threadIdx.x;
    const int sid  = blockIdx.x;
    const int lane = tid & 63;
    const int wid  = tid >> 6;

    if (tid < 128) {
        float s = pg3[tid] * rsqrtf(pv3[tid] + EPS_BN);
        sc3[tid] = s; sh3[tid] = (pb3[tid] - pm3[tid]) * s + pbe3[tid];
    }
    if (tid < 72) {   // zero halo rows
        Xh[tid] = 0; Xl[tid] = 0;
        Xh[129*72 + tid] = 0; Xl[129*72 + tid] = 0;
    }

    // ---- stage Y2 -> Xh/Xl (transpose + split), 4 chunks of 16 ci ----
    const float* ybase = Y2 + (size_t)sid * 8192;
    for (int c = 0; c < 4; ++c) {
        __syncthreads();                       // S reusable
        #pragma unroll
        for (int it = 0; it < 2; ++it) {
            int f = it*256 + tid;              // float4 idx in chunk [0,512)
            float4 v = ((const float4*)ybase)[c*512 + f];
            int ci_l = f >> 5;                 // 0..15
            int l4   = (f & 31) * 4;
            *(float4*)&S[ci_l*132 + l4] = v;   // 16B-aligned, conflict-free
        }
        __syncthreads();
        #pragma unroll
        for (int it = 0; it < 8; ++it) {
            int e = it*256 + tid;              // [0,2048)
            int ci_l = e & 15;
            int l    = e >> 4;                 // 0..127
            float x = S[ci_l*132 + l];
            unsigned uh, ul;
            bf16_split(x, uh, ul);
            int xi = (l + 1)*72 + c*16 + ci_l; // lane-fast ci -> conflict-free
            Xh[xi] = (short)uh;
            Xl[xi] = (short)ul;
        }
    }
    __syncthreads();

    // ---- MFMA main loop ----
    floatx4 acc[8][2] = {};
    const int nt0 = wid * 2, nt1 = wid * 2 + 1;
    const int mrow = lane & 15;
    const int kq   = (lane >> 4) * 8;

    for (int t = 0; t < 3; ++t) {
        for (int ks = 0; ks < 2; ++ks) {
            const int fb = (t*2 + ks) * 8;
            const short8 Wh0 = *(const short8*)(Wf3 + (((fb + nt0)*2 + 0)*512 + lane*8));
            const short8 Wl0 = *(const short8*)(Wf3 + (((fb + nt0)*2 + 1)*512 + lane*8));
            const short8 Wh1 = *(const short8*)(Wf3 + (((fb + nt1)*2 + 0)*512 + lane*8));
            const short8 Wl1 = *(const short8*)(Wf3 + (((fb + nt1)*2 + 1)*512 + lane*8));
            #pragma unroll
            for (int mt = 0; mt < 8; ++mt) {
                const int base = (mt*16 + mrow + t)*72 + ks*32 + kq;
                const short8 Ah = *(const short8*)(&Xh[base]);
                const short8 Al = *(const short8*)(&Xl[base]);
                acc[mt][0] = __builtin_amdgcn_mfma_f32_16x16x32_bf16(Ah, Wh0, acc[mt][0], 0, 0, 0);
                acc[mt][0] = __builtin_amdgcn_mfma_f32_16x16x32_bf16(Ah, Wl0, acc[mt][0], 0, 0, 0);
                acc[mt][0] = __builtin_amdgcn_mfma_f32_16x16x32_bf16(Al, Wh0, acc[mt][0], 0, 0, 0);
                acc[mt][0] = __builtin_amdgcn_mfma_f32_16x16x32_bf16(Al, Wl0, acc[mt][0], 0, 0, 0);
                acc[mt][1] = __builtin_amdgcn_mfma_f32_16x16x32_bf16(Ah, Wh1, acc[mt][1], 0, 0, 0);
                acc[mt][1] = __builtin_amdgcn_mfma_f32_16x16x32_bf16(Ah, Wl1, acc[mt][1], 0, 0, 0);
                acc[mt][1] = __builtin_amdgcn_mfma_f32_16x16x32_bf16(Al, Wh1, acc[mt][1], 0, 0, 0);
                acc[mt][1] = __builtin_amdgcn_mfma_f32_16x16x32_bf16(Al, Wl1, acc[mt][1], 0, 0, 0);
            }
        }
    }

    // ---- epilogue: BN + ReLU + pool2 + mean, all from C-fragments ----
    // C/D layout: n (co) = lane&15, m (l) = quad*4 + reg; reg pairs pool.
    const float sc0 = sc3[nt0*16 + mrow], shf0 = sh3[nt0*16 + mrow];
    const float sc1v = sc3[nt1*16 + mrow], shf1 = sh3[nt1*16 + mrow];
    float sum0 = 0.f, sum1 = 0.f;
    #pragma unroll
    for (int mt = 0; mt < 8; ++mt) {
        floatx4 d = acc[mt][0];
        sum0 += fmaxf(0.f, fmaxf(d[0]*sc0 + shf0, d[1]*sc0 + shf0));
        sum0 += fmaxf(0.f, fmaxf(d[2]*sc0 + shf0, d[3]*sc0 + shf0));
        d = acc[mt][1];
        sum1 += fmaxf(0.f, fmaxf(d[0]*sc1v + shf1, d[1]*sc1v + shf1));
        sum1 += fmaxf(0.f, fmaxf(d[2]*sc1v + shf1, d[3]*sc1v + shf1));
    }
    sum0 += __shfl_xor(sum0, 16); sum0 += __shfl_xor(sum0, 32);
    sum1 += __shfl_xor(sum1, 16); sum1 += __shfl_xor(sum1, 32);
    if (lane < 16) {
        featm[nt0*16 + lane] = sum0 * (1.0f / 64.0f);
        featm[nt1*16 + lane] = sum1 * (1.0f / 64.0f);
    }
    __syncthreads();

    // ---- linear 128->128 + BN + ReLU ----
    if (tid < 128) {
        const float* wr = pwf + (size_t)tid * 128;
        float s = 0.f;
        #pragma unroll 4
        for (int i = 0; i < 128; i += 4) {
            float4 w4 = *(const float4*)(wr + i);
            s += w4.x*featm[i] + w4.y*featm[i+1] + w4.z*featm[i+2] + w4.w*featm[i+3];
        }
        s += pbf[tid];
        s = (s - pmf[tid]) * (pgf[tid] * rsqrtf(pvf[tid] + EPS_BN)) + pbef[tid];
        featr[tid] = fmaxf(s, 0.f);
    }
    __syncthreads();

    // ---- L2 normalize ----
    if (tid < 128) {
        float ss = 0.f;
        for (int i = 0; i < 128; ++i) ss += featr[i] * featr[i];
        float n = fmaxf(sqrtf(ss), 1e-12f);
        feat_out[(size_t)sid * 128 + tid] = featr[tid] / n;
    }
}

// ===========================================================================
// MONOLITHIC FALLBACK — only if ws_size can't hold Y2 (unused in practice).
// ===========================================================================
__global__ __launch_bounds__(256) void encoder_mono(
    const float* __restrict__ s_img, const float* __restrict__ q_img,
    const float* __restrict__ pw1, const float* __restrict__ pb1,
    const float* __restrict__ pg1, const float* __restrict__ pbe1,
    const float* __restrict__ pm1, const float* __restrict__ pv1,
    const float* __restrict__ pw2, const float* __restrict__ pb2,
    const float* __restrict__ pg2, const float* __restrict__ pbe2,
    const float* __restrict__ pm2, const float* __restrict__ pv2,
    const float* __restrict__ pw3, const float* __restrict__ pb3,
    const float* __restrict__ pg3, const float* __restrict__ pbe3,
    const float* __restrict__ pm3, const float* __restrict__ pv3,
    const float* __restrict__ pwf, const float* __restrict__ pbf,
    const float* __restrict__ pgf, const float* __restrict__ pbef,
    const float* __restrict__ pmf, const float* __restrict__ pvf,
    float* __restrict__ feat_out)
{
    __shared__ float smem[16576];
    __shared__ float sc1[32], sh1[32], sc2[64], sh2[64], sc3[128], sh3[128];
    __shared__ float featm[128], featr[128];
    float* const I  = smem;
    float* const B2 = smem;
    float* const B1 = smem + 8320;
    float* const B3 = smem + 8320;

    const int tid = threadIdx.x;
    const int sid = blockIdx.x;
    const float* xin = (sid < NSUP) ? (s_img + (size_t)sid * 4096)
                                    : (q_img + (size_t)(sid - NSUP) * 4096);
    if (tid < 32) {
        float s = pg1[tid] * rsqrtf(pv1[tid] + EPS_BN);
        sc1[tid] = s; sh1[tid] = (pb1[tid] - pm1[tid]) * s + pbe1[tid];
    } else if (tid < 96) {
        int c = tid - 32;
        float s = pg2[c] * rsqrtf(pv2[c] + EPS_BN);
        sc2[c] = s; sh2[c] = (pb2[c] - pm2[c]) * s + pbe2[c];
    } else if (tid < 224) {
        int c = tid - 96;
        float s = pg3[c] * rsqrtf(pv3[c] + EPS_BN);
        sc3[c] = s; sh3[c] = (pb3[c] - pm3[c]) * s + pbe3[c];
    }
    if (tid < 32) { B1[tid*258] = 0.f; B1[tid*258 + 257] = 0.f; }
    #pragma unroll
    for (int k = 0; k < 4; ++k) {
        int p = k*256 + tid;
        float4 v = ((const float4*)xin)[p];
        int fi = p * 4;
        int ci = fi >> 9;
        int l  = fi & 511;
        float* dst = &I[ci*514 + 1 + l];
        dst[0] = v.x; dst[1] = v.y; dst[2] = v.z; dst[3] = v.w;
    }
    if (tid < 8) { I[tid*514] = 0.f; I[tid*514 + 513] = 0.f; }
    __syncthreads();
    {
        const int lp = tid;
        float a0[32], a1[32];
        #pragma unroll
        for (int c = 0; c < 32; ++c) { a0[c] = 0.f; a1[c] = 0.f; }
        #pragma unroll
        for (int ci = 0; ci < 8; ++ci) {
            const float x0 = I[ci*514 + 2*lp + 0];
            const float x1 = I[ci*514 + 2*lp + 1];
            const float x2 = I[ci*514 + 2*lp + 2];
            const float x3 = I[ci*514 + 2*lp + 3];
            #pragma unroll
            for (int co = 0; co < 32; ++co) {
                const float W0 = pw1[(co*8 + ci)*3 + 0];
                const float W1 = pw1[(co*8 + ci)*3 + 1];
                const float W2 = pw1[(co*8 + ci)*3 + 2];
                a0[co] += W0*x0 + W1*x1 + W2*x2;
                a1[co] += W0*x1 + W1*x2 + W2*x3;
            }
        }
        #pragma unroll
        for (int co = 0; co < 32; ++co) {
            float v = fmaxf(a0[co]*sc1[co] + sh1[co], a1[co]*sc1[co] + sh1[co]);
            B1[co*258 + 1 + lp] = fmaxf(v, 0.f);
        }
    }
    __syncthreads();
    {
        if (tid < 64) { B2[tid*130] = 0.f; B2[tid*130 + 129] = 0.f; }
        const int lp = tid & 127;
        const int cobase = __builtin_amdgcn_readfirstlane(tid >> 7) * 32;
        float a0[32], a1[32];
        #pragma unroll
        for (int c = 0; c < 32; ++c) { a0[c] = 0.f; a1[c] = 0.f; }
        for (int ci = 0; ci < 32; ++ci) {
            const float x0 = B1[ci*258 + 2*lp + 0];
            const float x1 = B1[ci*258 + 2*lp + 1];
            const float x2 = B1[ci*258 + 2*lp + 2];
            const float x3 = B1[ci*258 + 2*lp + 3];
            #pragma unroll
            for (int j = 0; j < 32; ++j) {
                const int co = cobase + j;
                const float W0 = pw2[(co*32 + ci)*3 + 0];
                const float W1 = pw2[(co*32 + ci)*3 + 1];
                const float W2 = pw2[(co*32 + ci)*3 + 2];
                a0[j] += W0*x0 + W1*x1 + W2*x2;
                a1[j] += W0*x1 + W1*x2 + W2*x3;
            }
        }
        #pragma unroll
        for (int j = 0; j < 32; ++j) {
            const int co = cobase + j;
            float v = fmaxf(a0[j]*sc2[co] + sh2[co], a1[j]*sc2[co] + sh2[co]);
            B2[co*130 + 1 + lp] = fmaxf(v, 0.f);
        }
    }
    __syncthreads();
    {
        const int lp = tid & 63;
        const int cobase = __builtin_amdgcn_readfirstlane(tid >> 6) * 32;
        float a0[32], a1[32];
        #pragma unroll
        for (int c = 0; c < 32; ++c) { a0[c] = 0.f; a1[c] = 0.f; }
        for (int ci = 0; ci < 64; ++ci) {
            const float x0 = B2[ci*130 + 2*lp + 0];
            const float x1 = B2[ci*130 + 2*lp + 1];
            const float x2 = B2[ci*130 + 2*lp + 2];
            const float x3 = B2[ci*130 + 2*lp + 3];
            #pragma unroll
            for (int j = 0; j < 32; ++j) {
                const int co = cobase + j;
                const float W0 = pw3[(co*64 + ci)*3 + 0];
                const float W1 = pw3[(co*64 + ci)*3 + 1];
                const float W2 = pw3[(co*64 + ci)*3 + 2];
                a0[j] += W0*x0 + W1*x1 + W2*x2;
                a1[j] += W0*x1 + W1*x2 + W2*x3;
            }
        }
        #pragma unroll
        for (int j = 0; j < 32; ++j) {
            const int co = cobase + j;
            float v = fmaxf(a0[j]*sc3[co] + sh3[co], a1[j]*sc3[co] + sh3[co]);
            B3[co*64 + lp] = fmaxf(v, 0.f);
        }
    }
    __syncthreads();
    if (tid < 128) {
        float s = 0.f;
        for (int i = 0; i < 64; ++i) {
            int lp = (i + tid) & 63;
            s += B3[tid*64 + lp];
        }
        featm[tid] = s * (1.0f / 64.0f);
    }
    __syncthreads();
    if (tid < 128) {
        const float* wr = pwf + (size_t)tid * 128;
        float s = 0.f;
        #pragma unroll 4
        for (int i = 0; i < 128; i += 4) {
            float4 w4 = *(const float4*)(wr + i);
            s += w4.x*featm[i] + w4.y*featm[i+1] + w4.z*featm[i+2] + w4.w*featm[i+3];
        }
        s += pbf[tid];
        s = (s - pmf[tid]) * (pgf[tid] * rsqrtf(pvf[tid] + EPS_BN)) + pbef[tid];
        featr[tid] = fmaxf(s, 0.f);
    }
    __syncthreads();
    if (tid < 128) {
        float ss = 0.f;
        for (int i = 0; i < 128; ++i) ss += featr[i] * featr[i];
        float n = fmaxf(sqrtf(ss), 1e-12f);
        feat_out[(size_t)sid * 128 + tid] = featr[tid] / n;
    }
}

// ---------------------------------------------------------------------------
__global__ __launch_bounds__(128) void proto_kernel(
    const float* __restrict__ feat_s, const int* __restrict__ s_lab,
    float* __restrict__ protos)
{
    const int b = blockIdx.x / NWAY;
    const int w = blockIdx.x % NWAY;
    const int f = threadIdx.x;
    const float* sf = feat_s + (size_t)b * NSHOTB * 128;
    const int* lab = s_lab + b * NSHOTB;
    float acc = 0.f;
    int cnt = 0;
    for (int s = 0; s < NSHOTB; ++s) {
        int lv = lab[s];
        if (lv == w) { acc += sf[s*128 + f]; cnt++; }
    }
    protos[(size_t)blockIdx.x * 128 + f] = acc / (float)cnt;
}

__global__ __launch_bounds__(256) void dist_kernel(
    const float* __restrict__ feat_q, const float* __restrict__ protos,
    float* __restrict__ out)
{
    int idx = blockIdx.x * 256 + threadIdx.x;
    if (idx >= 32 * NQB * NWAY) return;
    int b = idx / (NQB * NWAY);
    int r = idx - b * (NQB * NWAY);
    int q = r / NWAY;
    int w = r - q * NWAY;
    const float* qf = feat_q + (size_t)(b * NQB + q) * 128;
    const float* pp = protos + (size_t)(b * NWAY + w) * 128;
    float d2 = 0.f;
    #pragma unroll 4
    for (int i = 0; i < 128; ++i) { float d = qf[i] - pp[i]; d2 += d * d; }
    out[idx] = -sqrtf(fmaxf(d2, 0.f));
}

// ---------------------------------------------------------------------------
extern "C" void kernel_launch(void* const* d_in, const int* in_sizes, int n_in,
                              void* d_out, int out_size, void* d_ws, size_t ws_size,
                              hipStream_t stream) {
    const float* s_img = (const float*)d_in[0];
    const float* q_img = (const float*)d_in[1];
    const int*   s_lab = (const int*)d_in[2];
    const float* pw1  = (const float*)d_in[3];
    const float* pb1  = (const float*)d_in[4];
    const float* pg1  = (const float*)d_in[5];
    const float* pbe1 = (const float*)d_in[6];
    const float* pm1  = (const float*)d_in[7];
    const float* pv1  = (const float*)d_in[8];
    const float* pw2  = (const float*)d_in[9];
    const float* pb2  = (const float*)d_in[10];
    const float* pg2  = (const float*)d_in[11];
    const float* pbe2 = (const float*)d_in[12];
    const float* pm2  = (const float*)d_in[13];
    const float* pv2  = (const float*)d_in[14];
    const float* pw3  = (const float*)d_in[15];
    const float* pb3  = (const float*)d_in[16];
    const float* pg3  = (const float*)d_in[17];
    const float* pbe3 = (const float*)d_in[18];
    const float* pm3  = (const float*)d_in[19];
    const float* pv3  = (const float*)d_in[20];
    const float* pwf  = (const float*)d_in[21];
    const float* pbf  = (const float*)d_in[22];
    const float* pgf  = (const float*)d_in[23];
    const float* pbef = (const float*)d_in[24];
    const float* pmf  = (const float*)d_in[25];
    const float* pvf  = (const float*)d_in[26];

    const size_t y2_elems   = (size_t)NSAMP * 8192;
    const size_t feat_elems = (size_t)NSAMP * 128;
    const size_t prot_elems = (size_t)32 * NWAY * 128;
    const size_t wf3_floats = 49152 / 2;   // 49152 bf16 shorts
    const size_t need_split = (y2_elems + feat_elems + prot_elems + wf3_floats) * sizeof(float);

    float* out = (float*)d_out;

    if (ws_size >= need_split) {
        float* Y2     = (float*)d_ws;
        float* feat   = Y2 + y2_elems;
        float* protos = feat + feat_elems;
        unsigned short* Wf3 = (unsigned short*)(protos + prot_elems);

        prep_w3_kernel<<<96, 256, 0, stream>>>(pw3, Wf3);
        conv12_kernel<<<NSAMP, 256, 0, stream>>>(
            s_img, q_img,
            pw1, pb1, pg1, pbe1, pm1, pv1,
            pw2, pb2, pg2, pbe2, pm2, pv2,
            Y2);
        conv3tail_kernel<<<NSAMP, 256, 0, stream>>>(
            Y2, Wf3,
            pg3, pbe3, pb3, pm3, pv3,
            pwf, pbf, pgf, pbef, pmf, pvf,
            feat);
        proto_kernel<<<32 * NWAY, 128, 0, stream>>>(feat, s_lab, protos);
        dist_kernel<<<(32 * NQB * NWAY + 255) / 256, 256, 0, stream>>>(
            feat + (size_t)NSUP * 128, protos, out);
    } else {
        float* feat   = (float*)d_ws;
        float* protos = feat + feat_elems;
        encoder_mono<<<NSAMP, 256, 0, stream>>>(
            s_img, q_img,
            pw1, pb1, pg1, pbe1, pm1, pv1,
            pw2, pb2, pg2, pbe2, pm2, pv2,
            pw3, pb3, pg3, pbe3, pm3, pv3,
            pwf, pbf, pgf, pbef, pmf, pvf,
            feat);
        proto_kernel<<<32 * NWAY, 128, 0, stream>>>(feat, s_lab, protos);
        dist_kernel<<<(32 * NQB * NWAY + 255) / 256, 256, 0, stream>>>(
            feat + (size_t)NSUP * 128, protos, out);
    }
}

// Round 5
// 706.073 us; speedup vs baseline: 3.2327x; 1.7360x over previous
//
#include <hip/hip_runtime.h>
#include <math.h>

#define EPS_BN 1e-5f

// Problem constants: B=32, NS=200, NQ=100, C=8, L=512, H=32, F=128, N_WAY=20
#define NSUP   6400
#define NQRY   3200
#define NSAMP  9600
#define NWAY   20
#define NSHOTB 200
#define NQB    100

using short8  = __attribute__((ext_vector_type(8))) short;
using floatx4 = __attribute__((ext_vector_type(4))) float;

// split x into hi/lo bf16 (RNE both): x ~= h + l, |err| ~ 2^-17 |x|
__device__ __forceinline__ void bf16_split(float x, unsigned& uh, unsigned& ul) {
    unsigned u = __float_as_uint(x);
    uh = (u + 0x7FFFu + ((u >> 16) & 1u)) >> 16;
    float hf = __uint_as_float(uh << 16);
    float e  = x - hf;
    unsigned ue = __float_as_uint(e);
    ul = (ue + 0x7FFFu + ((ue >> 16) & 1u)) >> 16;
}

// ===========================================================================
// prep W2: fp32 [64][32][3] -> B-fragments, split hi/lo bf16.
// frag = (t*4 + nt)*2 + hl; elem (lane,j): co = nt*16+(lane&15), ci = (lane>>4)*8+j
// ===========================================================================
__global__ __launch_bounds__(256) void prep_w2_kernel(
    const float* __restrict__ w2, unsigned short* __restrict__ Wf2)
{
    int e = blockIdx.x * 512 + threadIdx.x;   // grid 24
    #pragma unroll
    for (int r = 0; r < 2; ++r, e += 256) {
        int frag = e >> 9;
        int off  = e & 511;
        int lane = off >> 3, j = off & 7;
        int hl = frag & 1;
        int f2 = frag >> 1;
        int nt = f2 & 3;
        int t  = f2 >> 2;
        int co = nt * 16 + (lane & 15);
        int ci = (lane >> 4) * 8 + j;
        float x = w2[(co * 32 + ci) * 3 + t];
        unsigned uh, ul;
        bf16_split(x, uh, ul);
        Wf2[e] = (unsigned short)(hl ? ul : uh);
    }
}

// ===========================================================================
// prep W3: fp32 [128][64][3] -> B-fragments (round-4, verified).
// frag = ((t*2+ks)*8 + nt)*2 + hl; co = nt*16+(lane&15), ci = ks*32+(lane>>4)*8+j
// ===========================================================================
__global__ __launch_bounds__(256) void prep_w3_kernel(
    const float* __restrict__ w3, unsigned short* __restrict__ Wf3)
{
    int e = blockIdx.x * 512 + threadIdx.x;   // grid 96
    #pragma unroll
    for (int r = 0; r < 2; ++r, e += 256) {
        int frag = e >> 9;
        int off  = e & 511;
        int lane = off >> 3, j = off & 7;
        int hl = frag & 1;
        int f2 = frag >> 1;
        int nt = f2 & 7;
        int f3 = f2 >> 3;
        int ks = f3 & 1;
        int t  = f3 >> 1;
        int co = nt * 16 + (lane & 15);
        int ci = ks * 32 + (lane >> 4) * 8 + j;
        float x = w3[(co * 64 + ci) * 3 + t];
        unsigned uh, ul;
        bf16_split(x, uh, ul);
        Wf3[e] = (unsigned short)(hl ? ul : uh);
    }
}

// ===========================================================================
// Fully fused encoder: conv1 (vector fp32) -> split-bf16 -> conv2 (MFMA)
// -> split-bf16 -> conv3 (MFMA) -> mean/linear/BN/ReLU/normalize.
// One block/sample, 256 threads. LDS union region 41280 B (I | B1 | X2
// time-multiplexed via syncthreads) + 2.8 KB scales -> 3 blocks/CU.
// ===========================================================================
__global__ __launch_bounds__(256, 3) void encoder_fused(
    const float* __restrict__ s_img, const float* __restrict__ q_img,
    const float* __restrict__ pw1, const float* __restrict__ pb1,
    const float* __restrict__ pg1, const float* __restrict__ pbe1,
    const float* __restrict__ pm1, const float* __restrict__ pv1,
    const float* __restrict__ pb2, const float* __restrict__ pg2,
    const float* __restrict__ pbe2, const float* __restrict__ pm2,
    const float* __restrict__ pv2, const unsigned short* __restrict__ Wf2,
    const float* __restrict__ pb3, const float* __restrict__ pg3,
    const float* __restrict__ pbe3, const float* __restrict__ pm3,
    const float* __restrict__ pv3, const unsigned short* __restrict__ Wf3,
    const float* __restrict__ pwf, const float* __restrict__ pbf,
    const float* __restrict__ pgf, const float* __restrict__ pbef,
    const float* __restrict__ pmf, const float* __restrict__ pvf,
    float* __restrict__ feat_out)
{
    // Union region, time-multiplexed:
    //   phase 1: I   = fp32 8 x 514 (16448 B)
    //   phase 2: B1h/B1l = bf16, 258 rows x 40 (stride 40 shorts = 80 B)
    //   phase 3: X2h/X2l = bf16, 130 rows x 72 (stride 72 shorts = 144 B)
    __shared__ __align__(16) char U[41280];
    float* const I   = (float*)U;
    short* const B1h = (short*)U;
    short* const B1l = (short*)(U + 20640);
    short* const X2h = (short*)U;
    short* const X2l = (short*)(U + 18720);
    __shared__ float sc1[32], sh1[32], sc2[64], sh2[64], sc3[128], sh3[128];
    __shared__ float featm[128], featr[128];

    const int tid  = threadIdx.x;
    const int sid  = blockIdx.x;
    const int lane = tid & 63;
    const int wid  = tid >> 6;
    const int mrow = lane & 15;
    const int quad = lane >> 4;
    const int kq   = quad * 8;

    const float* xin = (sid < NSUP) ? (s_img + (size_t)sid * 4096)
                                    : (q_img + (size_t)(sid - NSUP) * 4096);

    // ---- fold BN params ----
    if (tid < 32) {
        float s = pg1[tid] * rsqrtf(pv1[tid] + EPS_BN);
        sc1[tid] = s; sh1[tid] = (pb1[tid] - pm1[tid]) * s + pbe1[tid];
    } else if (tid < 96) {
        int c = tid - 32;
        float s = pg2[c] * rsqrtf(pv2[c] + EPS_BN);
        sc2[c] = s; sh2[c] = (pb2[c] - pm2[c]) * s + pbe2[c];
    } else if (tid < 224) {
        int c = tid - 96;
        float s = pg3[c] * rsqrtf(pv3[c] + EPS_BN);
        sc3[c] = s; sh3[c] = (pb3[c] - pm3[c]) * s + pbe3[c];
    }

    // ---- phase 1: stage input ----
    if (tid < 8) { I[tid*514] = 0.f; I[tid*514 + 513] = 0.f; }
    #pragma unroll
    for (int k = 0; k < 4; ++k) {
        int p = k*256 + tid;
        float4 v = ((const float4*)xin)[p];
        int fi = p * 4;
        int ci = fi >> 9;
        int l  = fi & 511;
        float* dst = &I[ci*514 + 1 + l];
        dst[0] = v.x; dst[1] = v.y; dst[2] = v.z; dst[3] = v.w;
    }
    __syncthreads();

    // ---- conv1 (vector fp32) -> pooled registers ----
    float p1[32];
    {
        const int lp = tid;
        float a0[32], a1[32];
        #pragma unroll
        for (int c = 0; c < 32; ++c) { a0[c] = 0.f; a1[c] = 0.f; }
        #pragma unroll
        for (int ci = 0; ci < 8; ++ci) {
            const float x0 = I[ci*514 + 2*lp + 0];
            const float x1 = I[ci*514 + 2*lp + 1];
            const float x2 = I[ci*514 + 2*lp + 2];
            const float x3 = I[ci*514 + 2*lp + 3];
            #pragma unroll
            for (int co = 0; co < 32; ++co) {
                const float W0 = pw1[(co*8 + ci)*3 + 0];
                const float W1 = pw1[(co*8 + ci)*3 + 1];
                const float W2 = pw1[(co*8 + ci)*3 + 2];
                a0[co] += W0*x0 + W1*x1 + W2*x2;
                a1[co] += W0*x1 + W1*x2 + W2*x3;
            }
        }
        #pragma unroll
        for (int co = 0; co < 32; ++co) {
            float v = fmaxf(a0[co]*sc1[co] + sh1[co], a1[co]*sc1[co] + sh1[co]);
            p1[co] = fmaxf(v, 0.f);
        }
    }
    __syncthreads();   // I dead

    // ---- phase 2: write B1 (split bf16, conv2 A-layout) ----
    {
        const int row = tid + 1;   // rows 1..256; halos 0, 257
        #pragma unroll
        for (int g = 0; g < 4; ++g) {
            short8 vh, vl;
            #pragma unroll
            for (int j = 0; j < 8; ++j) {
                unsigned uh, ul;
                bf16_split(p1[g*8 + j], uh, ul);
                vh[j] = (short)uh; vl[j] = (short)ul;
            }
            *(short8*)&B1h[row*40 + g*8] = vh;
            *(short8*)&B1l[row*40 + g*8] = vl;
        }
        if (tid < 40) {
            B1h[tid] = 0; B1l[tid] = 0;
            B1h[257*40 + tid] = 0; B1l[257*40 + tid] = 0;
        }
    }
    __syncthreads();

    // ---- conv2 MFMA: M=256(l), N=64(co), K=32(ci), 3 taps; wave w: nt=w ----
    floatx4 acc2[16] = {};
    for (int t = 0; t < 3; ++t) {
        const short8 Wh = *(const short8*)(Wf2 + (((t*4 + wid)*2 + 0)*512 + lane*8));
        const short8 Wl = *(const short8*)(Wf2 + (((t*4 + wid)*2 + 1)*512 + lane*8));
        #pragma unroll
        for (int mt = 0; mt < 16; ++mt) {
            const int base = (mt*16 + mrow + t)*40 + kq;
            const short8 Ah = *(const short8*)&B1h[base];
            const short8 Al = *(const short8*)&B1l[base];
            acc2[mt] = __builtin_amdgcn_mfma_f32_16x16x32_bf16(Ah, Wh, acc2[mt], 0, 0, 0);
            acc2[mt] = __builtin_amdgcn_mfma_f32_16x16x32_bf16(Ah, Wl, acc2[mt], 0, 0, 0);
            acc2[mt] = __builtin_amdgcn_mfma_f32_16x16x32_bf16(Al, Wh, acc2[mt], 0, 0, 0);
            acc2[mt] = __builtin_amdgcn_mfma_f32_16x16x32_bf16(Al, Wl, acc2[mt], 0, 0, 0);
        }
    }
    __syncthreads();   // B1 dead

    // ---- phase 3: conv2 epilogue -> X2 (BN+ReLU+pool2, split bf16) ----
    {
        const int co = wid*16 + mrow;
        const float sc = sc2[co], sh = sh2[co];
        #pragma unroll
        for (int mt = 0; mt < 16; ++mt) {
            floatx4 d = acc2[mt];
            float v0 = fmaxf(0.f, fmaxf(d[0]*sc + sh, d[1]*sc + sh));
            float v1 = fmaxf(0.f, fmaxf(d[2]*sc + sh, d[3]*sc + sh));
            const int r0 = mt*8 + quad*2 + 1;   // rows 1..128
            unsigned uh, ul;
            bf16_split(v0, uh, ul);
            X2h[r0*72 + co] = (short)uh; X2l[r0*72 + co] = (short)ul;
            bf16_split(v1, uh, ul);
            X2h[(r0+1)*72 + co] = (short)uh; X2l[(r0+1)*72 + co] = (short)ul;
        }
        if (tid < 72) {
            X2h[tid] = 0; X2l[tid] = 0;
            X2h[129*72 + tid] = 0; X2l[129*72 + tid] = 0;
        }
    }
    __syncthreads();

    // ---- conv3 MFMA: M=128, N=128, K=64(2 ks), 3 taps; wave w: nt {2w,2w+1} ----
    floatx4 acc3[8][2] = {};
    const int nt0 = wid * 2, nt1 = wid * 2 + 1;
    for (int t = 0; t < 3; ++t) {
        for (int ks = 0; ks < 2; ++ks) {
            const int fb = (t*2 + ks) * 8;
            const short8 Wh0 = *(const short8*)(Wf3 + (((fb + nt0)*2 + 0)*512 + lane*8));
            const short8 Wl0 = *(const short8*)(Wf3 + (((fb + nt0)*2 + 1)*512 + lane*8));
            const short8 Wh1 = *(const short8*)(Wf3 + (((fb + nt1)*2 + 0)*512 + lane*8));
            const short8 Wl1 = *(const short8*)(Wf3 + (((fb + nt1)*2 + 1)*512 + lane*8));
            #pragma unroll
            for (int mt = 0; mt < 8; ++mt) {
                const int base = (mt*16 + mrow + t)*72 + ks*32 + kq;
                const short8 Ah = *(const short8*)&X2h[base];
                const short8 Al = *(const short8*)&X2l[base];
                acc3[mt][0] = __builtin_amdgcn_mfma_f32_16x16x32_bf16(Ah, Wh0, acc3[mt][0], 0, 0, 0);
                acc3[mt][0] = __builtin_amdgcn_mfma_f32_16x16x32_bf16(Ah, Wl0, acc3[mt][0], 0, 0, 0);
                acc3[mt][0] = __builtin_amdgcn_mfma_f32_16x16x32_bf16(Al, Wh0, acc3[mt][0], 0, 0, 0);
                acc3[mt][0] = __builtin_amdgcn_mfma_f32_16x16x32_bf16(Al, Wl0, acc3[mt][0], 0, 0, 0);
                acc3[mt][1] = __builtin_amdgcn_mfma_f32_16x16x32_bf16(Ah, Wh1, acc3[mt][1], 0, 0, 0);
                acc3[mt][1] = __builtin_amdgcn_mfma_f32_16x16x32_bf16(Ah, Wl1, acc3[mt][1], 0, 0, 0);
                acc3[mt][1] = __builtin_amdgcn_mfma_f32_16x16x32_bf16(Al, Wh1, acc3[mt][1], 0, 0, 0);
                acc3[mt][1] = __builtin_amdgcn_mfma_f32_16x16x32_bf16(Al, Wl1, acc3[mt][1], 0, 0, 0);
            }
        }
    }

    // ---- conv3 epilogue: BN + ReLU + pool2 + mean from C-fragments ----
    {
        const float sc0 = sc3[nt0*16 + mrow], shf0 = sh3[nt0*16 + mrow];
        const float sc1v = sc3[nt1*16 + mrow], shf1 = sh3[nt1*16 + mrow];
        float sum0 = 0.f, sum1 = 0.f;
        #pragma unroll
        for (int mt = 0; mt < 8; ++mt) {
            floatx4 d = acc3[mt][0];
            sum0 += fmaxf(0.f, fmaxf(d[0]*sc0 + shf0, d[1]*sc0 + shf0));
            sum0 += fmaxf(0.f, fmaxf(d[2]*sc0 + shf0, d[3]*sc0 + shf0));
            d = acc3[mt][1];
            sum1 += fmaxf(0.f, fmaxf(d[0]*sc1v + shf1, d[1]*sc1v + shf1));
            sum1 += fmaxf(0.f, fmaxf(d[2]*sc1v + shf1, d[3]*sc1v + shf1));
        }
        sum0 += __shfl_xor(sum0, 16); sum0 += __shfl_xor(sum0, 32);
        sum1 += __shfl_xor(sum1, 16); sum1 += __shfl_xor(sum1, 32);
        if (lane < 16) {
            featm[nt0*16 + lane] = sum0 * (1.0f / 64.0f);
            featm[nt1*16 + lane] = sum1 * (1.0f / 64.0f);
        }
    }
    __syncthreads();

    // ---- linear 128->128 + BN + ReLU ----
    if (tid < 128) {
        const float* wr = pwf + (size_t)tid * 128;
        float s = 0.f;
        #pragma unroll 4
        for (int i = 0; i < 128; i += 4) {
            float4 w4 = *(const float4*)(wr + i);
            s += w4.x*featm[i] + w4.y*featm[i+1] + w4.z*featm[i+2] + w4.w*featm[i+3];
        }
        s += pbf[tid];
        s = (s - pmf[tid]) * (pgf[tid] * rsqrtf(pvf[tid] + EPS_BN)) + pbef[tid];
        featr[tid] = fmaxf(s, 0.f);
    }
    __syncthreads();

    // ---- L2 normalize ----
    if (tid < 128) {
        float ss = 0.f;
        for (int i = 0; i < 128; ++i) ss += featr[i] * featr[i];
        float n = fmaxf(sqrtf(ss), 1e-12f);
        feat_out[(size_t)sid * 128 + tid] = featr[tid] / n;
    }
}

// ---------------------------------------------------------------------------
__global__ __launch_bounds__(128) void proto_kernel(
    const float* __restrict__ feat_s, const int* __restrict__ s_lab,
    float* __restrict__ protos)
{
    const int b = blockIdx.x / NWAY;
    const int w = blockIdx.x % NWAY;
    const int f = threadIdx.x;
    const float* sf = feat_s + (size_t)b * NSHOTB * 128;
    const int* lab = s_lab + b * NSHOTB;
    float acc = 0.f;
    int cnt = 0;
    for (int s = 0; s < NSHOTB; ++s) {
        int lv = lab[s];
        if (lv == w) { acc += sf[s*128 + f]; cnt++; }
    }
    protos[(size_t)blockIdx.x * 128 + f] = acc / (float)cnt;
}

__global__ __launch_bounds__(256) void dist_kernel(
    const float* __restrict__ feat_q, const float* __restrict__ protos,
    float* __restrict__ out)
{
    int idx = blockIdx.x * 256 + threadIdx.x;
    if (idx >= 32 * NQB * NWAY) return;
    int b = idx / (NQB * NWAY);
    int r = idx - b * (NQB * NWAY);
    int q = r / NWAY;
    int w = r - q * NWAY;
    const float* qf = feat_q + (size_t)(b * NQB + q) * 128;
    const float* pp = protos + (size_t)(b * NWAY + w) * 128;
    float d2 = 0.f;
    #pragma unroll 4
    for (int i = 0; i < 128; ++i) { float d = qf[i] - pp[i]; d2 += d * d; }
    out[idx] = -sqrtf(fmaxf(d2, 0.f));
}

// ---------------------------------------------------------------------------
extern "C" void kernel_launch(void* const* d_in, const int* in_sizes, int n_in,
                              void* d_out, int out_size, void* d_ws, size_t ws_size,
                              hipStream_t stream) {
    const float* s_img = (const float*)d_in[0];
    const float* q_img = (const float*)d_in[1];
    const int*   s_lab = (const int*)d_in[2];
    const float* pw1  = (const float*)d_in[3];
    const float* pb1  = (const float*)d_in[4];
    const float* pg1  = (const float*)d_in[5];
    const float* pbe1 = (const float*)d_in[6];
    const float* pm1  = (const float*)d_in[7];
    const float* pv1  = (const float*)d_in[8];
    const float* pw2  = (const float*)d_in[9];
    const float* pb2  = (const float*)d_in[10];
    const float* pg2  = (const float*)d_in[11];
    const float* pbe2 = (const float*)d_in[12];
    const float* pm2  = (const float*)d_in[13];
    const float* pv2  = (const float*)d_in[14];
    const float* pw3  = (const float*)d_in[15];
    const float* pb3  = (const float*)d_in[16];
    const float* pg3  = (const float*)d_in[17];
    const float* pbe3 = (const float*)d_in[18];
    const float* pm3  = (const float*)d_in[19];
    const float* pv3  = (const float*)d_in[20];
    const float* pwf  = (const float*)d_in[21];
    const float* pbf  = (const float*)d_in[22];
    const float* pgf  = (const float*)d_in[23];
    const float* pbef = (const float*)d_in[24];
    const float* pmf  = (const float*)d_in[25];
    const float* pvf  = (const float*)d_in[26];

    const size_t feat_elems = (size_t)NSAMP * 128;      // fp32
    const size_t prot_elems = (size_t)32 * NWAY * 128;  // fp32
    const size_t wf2_shorts = 12288;                    // 24 frags x 512
    const size_t wf3_shorts = 49152;                    // 96 frags x 512

    float* feat   = (float*)d_ws;
    float* protos = feat + feat_elems;
    unsigned short* Wf2 = (unsigned short*)(protos + prot_elems);
    unsigned short* Wf3 = Wf2 + wf2_shorts;
    float* out = (float*)d_out;

    prep_w2_kernel<<<24, 256, 0, stream>>>(pw2, Wf2);
    prep_w3_kernel<<<96, 256, 0, stream>>>(pw3, Wf3);

    encoder_fused<<<NSAMP, 256, 0, stream>>>(
        s_img, q_img,
        pw1, pb1, pg1, pbe1, pm1, pv1,
        pb2, pg2, pbe2, pm2, pv2, Wf2,
        pb3, pg3, pbe3, pm3, pv3, Wf3,
        pwf, pbf, pgf, pbef, pmf, pvf,
        feat);

    proto_kernel<<<32 * NWAY, 128, 0, stream>>>(feat, s_lab, protos);

    dist_kernel<<<(32 * NQB * NWAY + 255) / 256, 256, 0, stream>>>(
        feat + (size_t)NSUP * 128, protos, out);
}